// Round 2
// baseline (512.456 us; speedup 1.0000x reference)
//
#include <hip/hip_runtime.h>
#include <math.h>

typedef unsigned short u16;
typedef unsigned int u32;
typedef __attribute__((ext_vector_type(8))) short short8;   // 8 bf16 = 4 VGPRs
typedef __attribute__((ext_vector_type(4))) float float4v;  // MFMA accum

// ---------- constants ----------
#define BATCH   8192
#define OBS     21
#define HID     512
#define NL      10
#define OVERALL 5632            // HID*(NL+1)
#define IN_DIM  5653            // OBS + OVERALL
#define OUT_DIM 5640            // OVERALL + ACT
#define ACT     8

// output element offsets (flat concat, fp32 elements)
#define O_PM   0
#define O_LS   65536
#define O_NH   131072
#define O_NM   (131072 + BATCH*OVERALL)     // 46268416
#define O_NLS  (O_NM + 65536)               // 46333952

// packed workspace: 10 x 512 x 512 bf16 weight blocks (K-contiguous)
#define WSP_TOTAL (10*512*512)
#define WSP_BYTES ((size_t)WSP_TOTAL * 2)

__device__ __forceinline__ u16 f2bf(float f) {
    u32 u = __float_as_uint(f);
    u32 r = (u + 0x7fffu + ((u >> 16) & 1u)) >> 16;   // RNE
    return (u16)r;
}
__device__ __forceinline__ u32 pkbf(float a, float b) {
    return (u32)f2bf(a) | ((u32)f2bf(b) << 16);
}
__device__ __forceinline__ void gload_lds16(const void* g, void* l) {
    __builtin_amdgcn_global_load_lds(
        (const __attribute__((address_space(1))) char*)g,
        (__attribute__((address_space(3))) char*)l, 16, 0, 0);
}

// ---------- kernel 0: repack banded W_mean blocks fp32 -> bf16 ----------
__global__ __launch_bounds__(256) void k_pack(const float* __restrict__ Wm,
                                              u16* __restrict__ ws) {
    int idx = blockIdx.x * 256 + threadIdx.x;
    if (idx >= WSP_TOTAL) return;
    int z = idx >> 18;
    int rem = idx & 262143;
    int n = rem >> 9, k = rem & 511;
    float v = Wm[(size_t)(512 * (z + 1) + n) * IN_DIM + OBS + 512 * z + k];
    ws[idx] = f2bf(v);
}

// ---------- kernel 1: main batched GEMM, blocks 1..10 (bias+relu epilogue) ----
#define BM 128
#define BN 128
#define BK 32
#define A_LD 40                 // padded LDS row (u16) -> 2-way bank alias only
__global__ __launch_bounds__(256, 2) void k_gemm(const float* __restrict__ X,
                                                 const float* __restrict__ Wm_raw,
                                                 const u16* __restrict__ Wp,
                                                 const float* __restrict__ b_mean,
                                                 float* __restrict__ out_h,
                                                 int packed) {
    __shared__ __attribute__((aligned(16))) u16 As[BM * A_LD];
    __shared__ __attribute__((aligned(16))) u16 Bs[BN * BK];
    int t = threadIdx.x;
    int wave = t >> 6, lane = t & 63;
    int quad = lane >> 4, r16 = lane & 15;
    int gm = blockIdx.x * BM;
    int gn = blockIdx.y * BN;
    int z = blockIdx.z;                       // band block i = z+1
    int wm = (wave >> 1) * 64;
    int wn = (wave & 1) * 64;
    int ar = t >> 1;                          // A staging row 0..127
    int ah = t & 1;                           // A staging half (16 floats)

    const float* Arow = X + (size_t)(gm + ar) * OVERALL + z * 512 + ah * 16;

    float4v acc[4][4];
#pragma unroll
    for (int i = 0; i < 4; i++)
#pragma unroll
        for (int j = 0; j < 4; j++) acc[i][j] = (float4v)0.f;

    for (int k0 = 0; k0 < 512; k0 += BK) {
        __syncthreads();                      // LDS WAR protection
        // ---- A tile: fp32 global -> cvt bf16 -> LDS ----
        {
            const float* ga = Arow + k0;
            float4 v0 = *(const float4*)(ga);
            float4 v1 = *(const float4*)(ga + 4);
            float4 v2 = *(const float4*)(ga + 8);
            float4 v3 = *(const float4*)(ga + 12);
            uint4 p0, p1;
            p0.x = pkbf(v0.x, v0.y); p0.y = pkbf(v0.z, v0.w);
            p0.z = pkbf(v1.x, v1.y); p0.w = pkbf(v1.z, v1.w);
            p1.x = pkbf(v2.x, v2.y); p1.y = pkbf(v2.z, v2.w);
            p1.z = pkbf(v3.x, v3.y); p1.w = pkbf(v3.z, v3.w);
            *(uint4*)&As[ar * A_LD + ah * 16] = p0;
            *(uint4*)&As[ar * A_LD + ah * 16 + 8] = p1;
        }
        // ---- B tile ----
        if (packed) {
#pragma unroll
            for (int it = 0; it < 2; ++it) {
                // lane l writes LDS at wave-uniform base + l*16
                int n = it * 64 + wave * 16 + (lane >> 2);
                int kk = (lane & 3) * 8;
                const u16* gb = Wp + (size_t)z * (512 * 512) + (size_t)(gn + n) * 512 + k0 + kk;
                gload_lds16(gb, (char*)Bs + it * 4096 + wave * 1024);
            }
        } else {
            int n = t >> 1, h = t & 1;
            const float* gb = Wm_raw + (size_t)(512 * (z + 1) + gn + n) * IN_DIM
                              + OBS + 512 * z + k0 + h * 16;
#pragma unroll
            for (int e = 0; e < 16; e += 2)
                *(u32*)&Bs[n * BK + h * 16 + e] = pkbf(gb[e], gb[e + 1]);
        }
        __syncthreads();                      // drains vmcnt/lgkmcnt

        short8 af[4], bf[4];
#pragma unroll
        for (int i = 0; i < 4; i++) {
            af[i] = *(const short8*)&As[(wm + i * 16 + r16) * A_LD + quad * 8];
            bf[i] = *(const short8*)&Bs[(wn + i * 16 + r16) * BK + quad * 8];
        }
#pragma unroll
        for (int i = 0; i < 4; i++)
#pragma unroll
            for (int j = 0; j < 4; j++)
                acc[i][j] = __builtin_amdgcn_mfma_f32_16x16x32_bf16(af[i], bf[j], acc[i][j], 0, 0, 0);
    }

    // epilogue: +bias, relu, fp32 store.  C/D: col=lane&15, row=quad*4+reg
    int colblock = 512 * (z + 1);
#pragma unroll
    for (int j = 0; j < 4; j++) {
        int n_loc = gn + wn + j * 16 + r16;
        float bias = b_mean[colblock + n_loc];
#pragma unroll
        for (int i = 0; i < 4; i++) {
            int m0 = gm + wm + i * 16 + quad * 4;
#pragma unroll
            for (int r = 0; r < 4; r++) {
                float v = acc[i][j][r] + bias;
                out_h[(size_t)(m0 + r) * OVERALL + colblock + n_loc] = fmaxf(v, 0.f);
            }
        }
    }
}

// ---------- kernel 2: band block 0 (obs -> new_hidden cols 0..511) ----------
__global__ __launch_bounds__(256) void k_block0(const float* __restrict__ obs,
                                                const float* __restrict__ Wm,
                                                const float* __restrict__ b_mean,
                                                float* __restrict__ out_h) {
    __shared__ float obs_s[8 * OBS];
    int t = threadIdx.x;
    int b0 = blockIdx.x * 8;
    if (t < 8 * OBS) obs_s[t] = obs[(size_t)b0 * OBS + t];
    __syncthreads();
#pragma unroll
    for (int half = 0; half < 2; ++half) {
        int n = half * 256 + t;
        float w[OBS];
#pragma unroll
        for (int k = 0; k < OBS; k++) w[k] = Wm[(size_t)n * IN_DIM + k];
        float bias = b_mean[n];
#pragma unroll 2
        for (int r = 0; r < 8; r++) {
            float a = bias;
#pragma unroll
            for (int k = 0; k < OBS; k++) a += obs_s[r * OBS + k] * w[k];
            out_h[(size_t)(b0 + r) * OVERALL + n] = fmaxf(a, 0.f);
        }
    }
}

// ---------- kernel 3: thin outputs (fp32 exact): new_mean + new_log_std -----
__global__ __launch_bounds__(256) void k_thin(const float* __restrict__ obs,
                                              const float* __restrict__ X,
                                              const float* __restrict__ Wm,
                                              const float* __restrict__ Wls,
                                              const float* __restrict__ b_mean,
                                              const float* __restrict__ b_logstd,
                                              float* __restrict__ out_mean,
                                              float* __restrict__ out_ls) {
    int t = threadIdx.x, wave = t >> 6, lane = t & 63;
    int b0 = (blockIdx.x * 4 + wave) * 4;       // 4 batch rows per wave

    float als[4][8], amn[4][8];
#pragma unroll
    for (int r = 0; r < 4; r++)
#pragma unroll
        for (int n = 0; n < 8; n++) { als[r][n] = 0.f; amn[r][n] = 0.f; }

    for (int j = 0; j < 22; j++) {              // K = 5632 in chunks of 256
        int k = j * 256 + lane * 4;
        float x[4][4];
#pragma unroll
        for (int r = 0; r < 4; r++)
            *(float4*)x[r] = *(const float4*)(X + (size_t)(b0 + r) * OVERALL + k);
#pragma unroll
        for (int n = 0; n < 8; n++) {
            const float* wp = Wls + (size_t)n * IN_DIM + OBS + k;   // not 16B aligned: scalar
            float w0 = wp[0], w1 = wp[1], w2 = wp[2], w3 = wp[3];
#pragma unroll
            for (int r = 0; r < 4; r++) {
                als[r][n] += x[r][0] * w0 + x[r][1] * w1 + x[r][2] * w2 + x[r][3] * w3;
            }
        }
        if (j >= 20) {                          // W_mean band block 11 -> new_mean
#pragma unroll
            for (int n = 0; n < 8; n++) {
                const float* wp = Wm + (size_t)(OVERALL + n) * IN_DIM + OBS + k;
                float w0 = wp[0], w1 = wp[1], w2 = wp[2], w3 = wp[3];
#pragma unroll
                for (int r = 0; r < 4; r++) {
                    amn[r][n] += x[r][0] * w0 + x[r][1] * w1 + x[r][2] * w2 + x[r][3] * w3;
                }
            }
        }
    }
    if (lane < OBS) {                           // obs contribution to log_std
#pragma unroll
        for (int r = 0; r < 4; r++) {
            float xo = obs[(size_t)(b0 + r) * OBS + lane];
#pragma unroll
            for (int n = 0; n < 8; n++)
                als[r][n] += xo * Wls[(size_t)n * IN_DIM + lane];
        }
    }
    // wave butterfly reduction
#pragma unroll
    for (int s = 1; s < 64; s <<= 1) {
#pragma unroll
        for (int r = 0; r < 4; r++)
#pragma unroll
            for (int n = 0; n < 8; n++) {
                als[r][n] += __shfl_xor(als[r][n], s, 64);
                amn[r][n] += __shfl_xor(amn[r][n], s, 64);
            }
    }
    if (lane == 0) {
#pragma unroll
        for (int r = 0; r < 4; r++)
#pragma unroll
            for (int n = 0; n < 8; n++) {
                out_ls[(size_t)(b0 + r) * ACT + n] = als[r][n] + b_logstd[n];
                out_mean[(size_t)(b0 + r) * ACT + n] = amn[r][n] + b_mean[OVERALL + n];
            }
    }
}

// ---------- kernel 4: prev_mean copy + log_std tanh (fp32 exact) ----------
__global__ __launch_bounds__(256) void k_small(const float* __restrict__ pm,
                                               const float* __restrict__ pls,
                                               float* __restrict__ o0,
                                               float* __restrict__ o1) {
    int i = blockIdx.x * 256 + threadIdx.x;     // 16384 threads x 4 floats
    float4 a = *(const float4*)(pm + (size_t)i * 4);
    *(float4*)(o0 + (size_t)i * 4) = a;
    float4 b = *(const float4*)(pls + (size_t)i * 4);
    float4 o;
    o.x = -5.f + 3.5f * (tanhf(b.x) + 1.f);
    o.y = -5.f + 3.5f * (tanhf(b.y) + 1.f);
    o.z = -5.f + 3.5f * (tanhf(b.z) + 1.f);
    o.w = -5.f + 3.5f * (tanhf(b.w) + 1.f);
    *(float4*)(o1 + (size_t)i * 4) = o;
}

extern "C" void kernel_launch(void* const* d_in, const int* in_sizes, int n_in,
                              void* d_out, int out_size, void* d_ws, size_t ws_size,
                              hipStream_t stream) {
    const float* obs         = (const float*)d_in[0];
    const float* hidden0     = (const float*)d_in[1];
    const float* prev_mean   = (const float*)d_in[2];
    const float* prev_logstd = (const float*)d_in[3];
    const float* W_mean      = (const float*)d_in[4];
    const float* b_mean      = (const float*)d_in[5];
    const float* W_logstd    = (const float*)d_in[6];
    const float* b_logstd    = (const float*)d_in[7];

    float* out   = (float*)d_out;
    float* o_pm  = out + O_PM;
    float* o_ls  = out + O_LS;
    float* o_nh  = out + O_NH;
    float* o_nm  = out + O_NM;
    float* o_nls = out + O_NLS;
    u16*   ws    = (u16*)d_ws;

    int packed = (ws != nullptr && ws_size >= WSP_BYTES) ? 1 : 0;

    if (packed) {
        k_pack<<<(WSP_TOTAL + 255) / 256, 256, 0, stream>>>(W_mean, ws);
    }
    k_gemm<<<dim3(BATCH / BM, 512 / BN, NL), 256, 0, stream>>>(
        hidden0, W_mean, ws, b_mean, o_nh, packed);
    k_block0<<<BATCH / 8, 256, 0, stream>>>(obs, W_mean, b_mean, o_nh);
    k_thin<<<BATCH / 16, 256, 0, stream>>>(obs, hidden0, W_mean, W_logstd,
                                           b_mean, b_logstd, o_nm, o_nls);
    k_small<<<64, 256, 0, stream>>>(prev_mean, prev_logstd, o_pm, o_ls);
}